// Round 10
// baseline (306.093 us; speedup 1.0000x reference)
//
#include <hip/hip_runtime.h>
#include <hip/hip_bf16.h>
#include <cstdint>
#include <cstddef>

#define BDIM 64
#define SDIM 512
#define HDIM 1024
#define MTOT (BDIM * SDIM)  // 32768

typedef __attribute__((ext_vector_type(8))) short short8;
typedef __attribute__((ext_vector_type(4))) float f32x4;

__device__ __forceinline__ unsigned int cvt2(float a, float b) {
  unsigned int r;
  asm("v_cvt_pk_bf16_f32 %0, %1, %2" : "=v"(r) : "v"(a), "v"(b));
  return r;
}

__device__ __forceinline__ void gld_lds16(const void* g, void* l) {
  __builtin_amdgcn_global_load_lds(
      (const __attribute__((address_space(1))) unsigned int*)g,
      (__attribute__((address_space(3))) unsigned int*)l, 16, 0, 0);
}

// tanh via hw exp2 + rcp: tanh(x) = 1 - 2/(e^{2x}+1). |err| ~1e-6, correct sat.
__device__ __forceinline__ float fast_tanh(float x) {
  const float e = __builtin_exp2f(x * 2.88539008f);  // 2*log2(e)
  return 1.0f - 2.0f * __builtin_amdgcn_rcpf(e + 1.0f);
}

// ---------- prep bodies (proven r2-r9) ----------
__device__ __forceinline__ void w2_body(const float* __restrict__ W,
                                        char* __restrict__ w2s, int bx, int tid) {
  const int n = bx * 2 + (tid >> 7);
  const int g = tid & 127;
  const int kt = g >> 3, gi = g & 7;
  const float* src = W + (size_t)n * 2048 + 1024 + g * 8;
  const float4 f0 = *reinterpret_cast<const float4*>(src);
  const float4 f1 = *reinterpret_cast<const float4*>(src + 4);
  uint4 u = make_uint4(cvt2(f0.x, f0.y), cvt2(f0.z, f0.w),
                       cvt2(f1.x, f1.y), cvt2(f1.z, f1.w));
  const int nblk = n >> 7, row = n & 127;
  const size_t off = ((size_t)(nblk * 16 + kt) * 128 + row) * 128 +
                     (size_t)(gi ^ (row & 7)) * 16;
  *reinterpret_cast<uint4*>(w2s + off) = u;
}

__device__ __forceinline__ void a_body(const float* __restrict__ hidden,
                                       const float* __restrict__ W,
                                       const float* __restrict__ bias,
                                       float* __restrict__ A, float* hl,
                                       int bx, int tid) {
  const int hc = bx & 3, b = bx >> 2;
  *reinterpret_cast<float4*>(&hl[tid * 4]) =
      *reinterpret_cast<const float4*>(hidden + (size_t)b * HDIM + tid * 4);
  __syncthreads();
  const int h = hc * 256 + tid;
  const float* wr = W + (size_t)h * 2048;
  float a0 = 0.f, a1 = 0.f, a2 = 0.f, a3 = 0.f;
  for (int k = 0; k < HDIM; k += 16) {
    const float4 w0 = *reinterpret_cast<const float4*>(wr + k);
    const float4 w1 = *reinterpret_cast<const float4*>(wr + k + 4);
    const float4 w2 = *reinterpret_cast<const float4*>(wr + k + 8);
    const float4 w3 = *reinterpret_cast<const float4*>(wr + k + 12);
    a0 += w0.x * hl[k]      + w0.y * hl[k + 1]  + w0.z * hl[k + 2]  + w0.w * hl[k + 3];
    a1 += w1.x * hl[k + 4]  + w1.y * hl[k + 5]  + w1.z * hl[k + 6]  + w1.w * hl[k + 7];
    a2 += w2.x * hl[k + 8]  + w2.y * hl[k + 9]  + w2.z * hl[k + 10] + w2.w * hl[k + 11];
    a3 += w3.x * hl[k + 12] + w3.y * hl[k + 13] + w3.z * hl[k + 14] + w3.w * hl[k + 15];
  }
  A[(size_t)b * HDIM + h] = bias[h] + ((a0 + a1) + (a2 + a3));
}

// ---- small prep: [0,512) W2 tiles | [512,768) A ----
__global__ __launch_bounds__(256) void prep_small_kernel(const float* __restrict__ W,
                                                         const float* __restrict__ hidden,
                                                         const float* __restrict__ bias,
                                                         char* __restrict__ w2s,
                                                         float* __restrict__ A) {
  __shared__ float hl[HDIM];
  const int bid = blockIdx.x;
  const int tid = threadIdx.x;
  if (bid < 512) w2_body(W, w2s, bid, tid);
  else a_body(hidden, W, bias, A, hl, bid - 512, tid);
}

// ---- main GEMM: 128x128 tile, 4 waves (2m x 2n, 64x64 each), BK=64.
//      A: direct global f32 -> cvt_pk -> MFMA regs (no LDS), 1-subphase pipeline.
//      B: w2s swizzled tiles via global_load_lds, dbuf, 1 barrier/K-tile. ----
__global__ __launch_bounds__(256, 3) void gemm_rega_kernel(const float* __restrict__ enc,
                                                           const char* __restrict__ w2s,
                                                           const float* __restrict__ A,
                                                           const float* __restrict__ v,
                                                           float* __restrict__ sp) {
  __shared__ __align__(16) unsigned short Bs[2][128][64];  // 32 KB dbuf
  __shared__ float red2[2][128];                           // 1 KB

  const int bid = blockIdx.x;
  const int lg = (bid & 7) * 256 + (bid >> 3);  // XCD swizzle, 2048 % 8 == 0
  const int nblk = lg & 7, mstrip = lg >> 3;
  const int m0 = mstrip * 128, n0 = nblk * 128;
  const int b = m0 >> 9;  // 128-row strip within one batch row (512 % 128 == 0)

  const int tid = threadIdx.x;
  const int w = tid >> 6, l = tid & 63;
  const int wm = w >> 1, wn = w & 1;  // 2 x 2 wave grid
  const int lr = l & 15, lk = l >> 4;

  f32x4 acc[4][4];
#pragma unroll
  for (int i = 0; i < 4; ++i)
#pragma unroll
    for (int j = 0; j < 4; ++j) acc[i][j] = (f32x4){0.f, 0.f, 0.f, 0.f};

  const char* bT = w2s + (size_t)(nblk * 16) * 16384;
  // A fragment base: row = m0 + wm*64 + f*16 + lr, k = kt*64 + ks*32 + lk*8
  const float* aBase = enc + (size_t)(m0 + wm * 64 + lr) * HDIM + lk * 8;

#define STAGE(kt_, buf_)                                              \
  do {                                                                \
    const char* s_ = bT + (size_t)(kt_) * 16384 + tid * 16;           \
    char* d_ = (char*)&Bs[(buf_)][0][0] + w * 1024;                   \
    gld_lds16(s_, d_);                                                \
    gld_lds16(s_ + 4096, d_ + 4096);                                  \
    gld_lds16(s_ + 8192, d_ + 8192);                                  \
    gld_lds16(s_ + 12288, d_ + 12288);                                \
  } while (0)

// load frags f0_ and f0_+1 for (kt_, ks_) into 4 named float4
#define LOADP(f0_, ks_, kt_, pa, pb, pc, pd)                                   \
  do {                                                                         \
    const float* p_ = aBase + (size_t)(f0_) * 16 * HDIM + (kt_) * 64 + (ks_) * 32; \
    pa = *reinterpret_cast<const float4*>(p_);                                 \
    pb = *reinterpret_cast<const float4*>(p_ + 4);                             \
    const float* q_ = p_ + 16 * HDIM;                                          \
    pc = *reinterpret_cast<const float4*>(q_);                                 \
    pd = *reinterpret_cast<const float4*>(q_ + 4);                             \
  } while (0)

#define CVTFR(pa, pb, dst)                                                     \
  do {                                                                         \
    uint4 u_ = make_uint4(cvt2((pa).x, (pa).y), cvt2((pa).z, (pa).w),          \
                          cvt2((pb).x, (pb).y), cvt2((pb).z, (pb).w));         \
    dst = *reinterpret_cast<short8*>(&u_);                                     \
  } while (0)

#define BFREAD(ks_, cur_)                                                      \
  do {                                                                         \
    _Pragma("unroll") for (int j = 0; j < 4; ++j) {                            \
      const int rb_ = wn * 64 + j * 16 + lr;                                   \
      const int gb_ = ((ks_) * 4 + lk) ^ (rb_ & 7);                            \
      bfv[j] = *reinterpret_cast<const short8*>(                               \
          (const char*)&Bs[(cur_)][0][0] + rb_ * 128 + gb_ * 16);              \
    }                                                                          \
  } while (0)

#define MFMA2(F0, F1)                                                          \
  do {                                                                         \
    _Pragma("unroll") for (int j = 0; j < 4; ++j)                              \
      acc[F0][j] = __builtin_amdgcn_mfma_f32_16x16x32_bf16(af0, bfv[j], acc[F0][j], 0, 0, 0); \
    _Pragma("unroll") for (int j = 0; j < 4; ++j)                              \
      acc[F1][j] = __builtin_amdgcn_mfma_f32_16x16x32_bf16(af1, bfv[j], acc[F1][j], 0, 0, 0); \
  } while (0)

  // prologue: B tile 0
  STAGE(0, 0);

  for (int kt = 0; kt < 16; ++kt) {
    const int cur = kt & 1;
    __syncthreads();  // B(kt) resident; drain waits nothing unconsumed
    if (kt < 15) STAGE(kt + 1, cur ^ 1);

    float4 a0, a1, a2, a3, b0, b1, b2, b3;
    short8 af0, af1;
    short8 bfv[4];

    // sp0: issue (ks0, f0-1); read bf(ks0)
    LOADP(0, 0, kt, a0, a1, a2, a3);
    BFREAD(0, cur);
    // sp1: issue (ks0, f2-3); consume a* -> frags 0,1
    LOADP(2, 0, kt, b0, b1, b2, b3);
    CVTFR(a0, a1, af0); CVTFR(a2, a3, af1);
    MFMA2(0, 1);
    // sp2: issue (ks1, f0-1); consume b* -> frags 2,3
    LOADP(0, 1, kt, a0, a1, a2, a3);
    CVTFR(b0, b1, af0); CVTFR(b2, b3, af1);
    MFMA2(2, 3);
    // sp3: issue (ks1, f2-3); read bf(ks1); consume a* -> frags 0,1
    LOADP(2, 1, kt, b0, b1, b2, b3);
    BFREAD(1, cur);
    CVTFR(a0, a1, af0); CVTFR(a2, a3, af1);
    MFMA2(0, 1);
    // sp4: consume b* -> frags 2,3
    CVTFR(b0, b1, af0); CVTFR(b2, b3, af1);
    MFMA2(2, 3);
  }
#undef STAGE
#undef LOADP
#undef CVTFR
#undef BFREAD
#undef MFMA2

  // ---- epilogue: partial[m] = sum over this block's 128 n of v[n]*tanh(C+A) ----
  float a_n[4], v_n[4];
#pragma unroll
  for (int j = 0; j < 4; ++j) {
    const int n = wn * 64 + j * 16 + lr;
    a_n[j] = A[(size_t)b * HDIM + n0 + n];
    v_n[j] = v[n0 + n];
  }
#pragma unroll
  for (int f = 0; f < 4; ++f) {
#pragma unroll
    for (int r = 0; r < 4; ++r) {
      float s = 0.f;
#pragma unroll
      for (int j = 0; j < 4; ++j)
        s += v_n[j] * fast_tanh(acc[f][j][r] + a_n[j]);
      s += __shfl_xor(s, 1);
      s += __shfl_xor(s, 2);
      s += __shfl_xor(s, 4);
      s += __shfl_xor(s, 8);
      if (lr == 0 && wn == 0) red2[0][wm * 64 + f * 16 + lk * 4 + r] = s;
      if (lr == 0 && wn == 1) red2[1][wm * 64 + f * 16 + lk * 4 + r] = s;
    }
  }
  __syncthreads();
  if (tid < 128)
    sp[(size_t)nblk * MTOT + m0 + tid] = red2[0][tid] + red2[1][tid];
}

// ---- softmax over s (512) per b; sums 8 partials ----
__global__ __launch_bounds__(512) void softmax8_kernel(const float* __restrict__ sp,
                                                       float* __restrict__ wts) {
  const int b = blockIdx.x, s = threadIdx.x;
  float sc = 0.f;
#pragma unroll
  for (int j = 0; j < 8; ++j) sc += sp[(size_t)j * MTOT + b * SDIM + s];
  float m = sc;
#pragma unroll
  for (int d = 1; d < 64; d <<= 1) m = fmaxf(m, __shfl_xor(m, d));
  __shared__ float redm[8], reds[8];
  if ((s & 63) == 0) redm[s >> 6] = m;
  __syncthreads();
  m = redm[0];
#pragma unroll
  for (int j = 1; j < 8; ++j) m = fmaxf(m, redm[j]);
  const float e = expf(sc - m);
  float sum = e;
#pragma unroll
  for (int d = 1; d < 64; d <<= 1) sum += __shfl_xor(sum, d);
  if ((s & 63) == 0) reds[s >> 6] = sum;
  __syncthreads();
  float tot = 0.f;
#pragma unroll
  for (int j = 0; j < 8; ++j) tot += reds[j];
  wts[(size_t)b * SDIM + s] = e / tot;
}

// ---- context[b,h] = sum_s w[b,s]*enc[b,s,h]; float2/lane ----
__global__ __launch_bounds__(256) void context_kernel(const float* __restrict__ enc,
                                                      const float* __restrict__ wts,
                                                      float* __restrict__ ctx) {
  const int hc = blockIdx.x;  // 0..1
  const int b  = blockIdx.y;  // 0..63
  const int t  = threadIdx.x;
  __shared__ float wl[SDIM];
  wl[t] = wts[(size_t)b * SDIM + t];
  wl[t + 256] = wts[(size_t)b * SDIM + 256 + t];
  __syncthreads();
  const int h = hc * 512 + t * 2;
  const float* e0 = enc + (size_t)b * SDIM * HDIM + h;
  float x0 = 0.f, y0 = 0.f, x1 = 0.f, y1 = 0.f;
  for (int s = 0; s < SDIM; s += 2) {
    const float2 v0 = *reinterpret_cast<const float2*>(e0 + (size_t)s * HDIM);
    const float2 v1 = *reinterpret_cast<const float2*>(e0 + (size_t)(s + 1) * HDIM);
    x0 += wl[s] * v0.x;     y0 += wl[s] * v0.y;
    x1 += wl[s + 1] * v1.x; y1 += wl[s + 1] * v1.y;
  }
  ctx[(size_t)b * HDIM + h]     = x0 + x1;
  ctx[(size_t)b * HDIM + h + 1] = y0 + y1;
}

extern "C" void kernel_launch(void* const* d_in, const int* in_sizes, int n_in,
                              void* d_out, int out_size, void* d_ws, size_t ws_size,
                              hipStream_t stream) {
  const float* hidden = (const float*)d_in[0];
  const float* enc    = (const float*)d_in[1];
  const float* W      = (const float*)d_in[2];
  const float* bias   = (const float*)d_in[3];
  const float* v      = (const float*)d_in[4];

  float* ctx = (float*)d_out;                // [64*1024] context
  float* wts = (float*)d_out + BDIM * HDIM;  // [64*512] attention weights

  char* ws = (char*)d_ws;
  char* w2s = ws;                                                   // 2 MB swizzled W2 tiles
  float* A  = (float*)(ws + (size_t)2 * 1024 * 1024);               // 256 KB
  float* sp = (float*)(ws + (size_t)2 * 1024 * 1024 + 256 * 1024);  // 1 MB (8 partials)

  hipLaunchKernelGGL(prep_small_kernel, dim3(768), dim3(256), 0, stream,
                     W, hidden, bias, w2s, A);
  hipLaunchKernelGGL(gemm_rega_kernel, dim3(2048), dim3(256), 0, stream, enc, w2s, A, v, sp);
  hipLaunchKernelGGL(softmax8_kernel, dim3(64), dim3(512), 0, stream, sp, wts);
  hipLaunchKernelGGL(context_kernel, dim3(2, 64), dim3(256), 0, stream, enc, wts, ctx);
}

// Round 11
// 155.462 us; speedup vs baseline: 1.9689x; 1.9689x over previous
//
#include <hip/hip_runtime.h>
#include <hip/hip_bf16.h>
#include <cstdint>
#include <cstddef>

#define BDIM 64
#define SDIM 512
#define HDIM 1024
#define MTOT (BDIM * SDIM)  // 32768

typedef __attribute__((ext_vector_type(8))) short short8;
typedef __attribute__((ext_vector_type(4))) float f32x4;

__device__ __forceinline__ unsigned int cvt2(float a, float b) {
  unsigned int r;
  asm("v_cvt_pk_bf16_f32 %0, %1, %2" : "=v"(r) : "v"(a), "v"(b));
  return r;
}

__device__ __forceinline__ void gld_lds16(const void* g, void* l) {
  __builtin_amdgcn_global_load_lds(
      (const __attribute__((address_space(1))) unsigned int*)g,
      (__attribute__((address_space(3))) unsigned int*)l, 16, 0, 0);
}

// tanh via hw exp2 + rcp: tanh(x) = 1 - 2/(e^{2x}+1). |err| ~1e-6, correct sat.
__device__ __forceinline__ float fast_tanh(float x) {
  const float e = __builtin_exp2f(x * 2.88539008f);  // 2*log2(e)
  return 1.0f - 2.0f * __builtin_amdgcn_rcpf(e + 1.0f);
}

// ---------- prep bodies (proven r2-r10) ----------
__device__ __forceinline__ void w2_body(const float* __restrict__ W,
                                        char* __restrict__ w2s, int bx, int tid) {
  const int n = bx * 2 + (tid >> 7);
  const int g = tid & 127;
  const int kt = g >> 3, gi = g & 7;
  const float* src = W + (size_t)n * 2048 + 1024 + g * 8;
  const float4 f0 = *reinterpret_cast<const float4*>(src);
  const float4 f1 = *reinterpret_cast<const float4*>(src + 4);
  uint4 u = make_uint4(cvt2(f0.x, f0.y), cvt2(f0.z, f0.w),
                       cvt2(f1.x, f1.y), cvt2(f1.z, f1.w));
  const int nblk = n >> 7, row = n & 127;
  const size_t off = ((size_t)(nblk * 16 + kt) * 128 + row) * 128 +
                     (size_t)(gi ^ (row & 7)) * 16;
  *reinterpret_cast<uint4*>(w2s + off) = u;
}

__device__ __forceinline__ void a_body(const float* __restrict__ hidden,
                                       const float* __restrict__ W,
                                       const float* __restrict__ bias,
                                       float* __restrict__ A, float* hl,
                                       int bx, int tid) {
  const int hc = bx & 3, b = bx >> 2;
  *reinterpret_cast<float4*>(&hl[tid * 4]) =
      *reinterpret_cast<const float4*>(hidden + (size_t)b * HDIM + tid * 4);
  __syncthreads();
  const int h = hc * 256 + tid;
  const float* wr = W + (size_t)h * 2048;
  float a0 = 0.f, a1 = 0.f, a2 = 0.f, a3 = 0.f;
  for (int k = 0; k < HDIM; k += 16) {
    const float4 w0 = *reinterpret_cast<const float4*>(wr + k);
    const float4 w1 = *reinterpret_cast<const float4*>(wr + k + 4);
    const float4 w2 = *reinterpret_cast<const float4*>(wr + k + 8);
    const float4 w3 = *reinterpret_cast<const float4*>(wr + k + 12);
    a0 += w0.x * hl[k]      + w0.y * hl[k + 1]  + w0.z * hl[k + 2]  + w0.w * hl[k + 3];
    a1 += w1.x * hl[k + 4]  + w1.y * hl[k + 5]  + w1.z * hl[k + 6]  + w1.w * hl[k + 7];
    a2 += w2.x * hl[k + 8]  + w2.y * hl[k + 9]  + w2.z * hl[k + 10] + w2.w * hl[k + 11];
    a3 += w3.x * hl[k + 12] + w3.y * hl[k + 13] + w3.z * hl[k + 14] + w3.w * hl[k + 15];
  }
  A[(size_t)b * HDIM + h] = bias[h] + ((a0 + a1) + (a2 + a3));
}

// ---- small prep: [0,512) W2 tiles | [512,768) A ----
__global__ __launch_bounds__(256) void prep_small_kernel(const float* __restrict__ W,
                                                         const float* __restrict__ hidden,
                                                         const float* __restrict__ bias,
                                                         char* __restrict__ w2s,
                                                         float* __restrict__ A) {
  __shared__ float hl[HDIM];
  const int bid = blockIdx.x;
  const int tid = threadIdx.x;
  if (bid < 512) w2_body(W, w2s, bid, tid);
  else a_body(hidden, W, bias, A, hl, bid - 512, tid);
}

// ---- main GEMM: 128x128 tile, 4 waves (2m x 2n), BK=64, single-buffer
//      2-barrier loop (m97 structure), 3 blocks/CU.
//      A: enc f32 DMA'd to LDS with pre-swizzled per-lane global src (no prepass),
//         layout Af[2 ks-planes][128 rows][128B], slot = g ^ (row&7);
//         converted to bf16 in-reg after ds_read_b128.
//      B: prestaged swizzled bf16 tiles (w2s) via linear DMA. ----
__global__ __launch_bounds__(256, 3) void gemm_f32lds_kernel(const float* __restrict__ enc,
                                                             const char* __restrict__ w2s,
                                                             const float* __restrict__ A,
                                                             const float* __restrict__ v,
                                                             float* __restrict__ sp) {
  __shared__ __align__(16) char Af[32768];                 // A tile, f32, swizzled granules
  __shared__ __align__(16) unsigned short Bs[128][64];     // 16 KB
  __shared__ float red2[2][128];                           // 1 KB

  const int bid = blockIdx.x;
  const int lg = (bid & 7) * 256 + (bid >> 3);  // XCD swizzle, 2048 % 8 == 0
  const int nblk = lg & 7, mstrip = lg >> 3;
  const int m0 = mstrip * 128, n0 = nblk * 128;
  const int b = m0 >> 9;

  const int tid = threadIdx.x;
  const int w = tid >> 6, l = tid & 63;
  const int wm = w >> 1, wn = w & 1;  // 2 x 2 wave grid
  const int lr = l & 15, lk = l >> 4;

  f32x4 acc[4][4];
#pragma unroll
  for (int i = 0; i < 4; ++i)
#pragma unroll
    for (int j = 0; j < 4; ++j) acc[i][j] = (f32x4){0.f, 0.f, 0.f, 0.f};

  const char* bT = w2s + (size_t)(nblk * 16) * 16384;

  // --- A staging: 8 gload_lds stmts; per-lane pre-swizzled global source ---
  // linear LDS offset o = i*4096 + w*1024 + l*16 ; plane = o>>14, row = (o>>7)&127,
  // slot = (o>>4)&7, logical granule g = slot ^ (row&7);
  // src float-offset = (m0+row)*1024 + plane*32 + g*4 (+ kt*64).
  int afo[8];
#pragma unroll
  for (int i = 0; i < 8; ++i) {
    const int o = i * 4096 + w * 1024 + l * 16;
    const int plane = o >> 14, row = (o >> 7) & 127, slot = (o >> 4) & 7;
    const int g = slot ^ (row & 7);
    afo[i] = (m0 + row) * 1024 + plane * 32 + g * 4;
  }

#define STAGE_A(kt_)                                                       \
  do {                                                                     \
    _Pragma("unroll") for (int i_ = 0; i_ < 8; ++i_)                       \
      gld_lds16(enc + (size_t)afo[i_] + (kt_)*64,                          \
                Af + i_ * 4096 + w * 1024);                                \
  } while (0)

#define STAGE_B(kt_)                                                       \
  do {                                                                     \
    const char* s_ = bT + (size_t)(kt_)*16384 + w * 1024 + l * 16;         \
    char* d_ = (char*)&Bs[0][0] + w * 1024;                                \
    gld_lds16(s_, d_);                                                     \
    gld_lds16(s_ + 4096, d_ + 4096);                                       \
    gld_lds16(s_ + 8192, d_ + 8192);                                       \
    gld_lds16(s_ + 12288, d_ + 12288);                                     \
  } while (0)

  for (int kt = 0; kt < 16; ++kt) {
    __syncthreads();  // all waves done reading previous tile
    STAGE_A(kt);
    STAGE_B(kt);
    __syncthreads();  // implicit vmcnt(0): tile resident

#pragma unroll
    for (int ks = 0; ks < 2; ++ks) {
      short8 bfv[4];
#pragma unroll
      for (int j = 0; j < 4; ++j) {
        const int rb = wn * 64 + j * 16 + lr;
        const int gb = (ks * 4 + lk) ^ (rb & 7);
        bfv[j] = *reinterpret_cast<const short8*>(
            (const char*)&Bs[0][0] + rb * 128 + gb * 16);
      }
#pragma unroll
      for (int f = 0; f < 4; ++f) {
        const int ra = wm * 64 + f * 16 + lr;
        const int rx = ra & 7;
        const char* ap = Af + ks * 16384 + ra * 128;
        const float4 x = *reinterpret_cast<const float4*>(ap + ((2 * lk) ^ rx) * 16);
        const float4 y = *reinterpret_cast<const float4*>(ap + ((2 * lk + 1) ^ rx) * 16);
        uint4 u = make_uint4(cvt2(x.x, x.y), cvt2(x.z, x.w),
                             cvt2(y.x, y.y), cvt2(y.z, y.w));
        const short8 af = *reinterpret_cast<short8*>(&u);
#pragma unroll
        for (int j = 0; j < 4; ++j)
          acc[f][j] = __builtin_amdgcn_mfma_f32_16x16x32_bf16(af, bfv[j], acc[f][j], 0, 0, 0);
      }
    }
  }
#undef STAGE_A
#undef STAGE_B

  // ---- epilogue: partial[m] = sum over this block's 128 n of v[n]*tanh(C+A) ----
  float a_n[4], v_n[4];
#pragma unroll
  for (int j = 0; j < 4; ++j) {
    const int n = wn * 64 + j * 16 + lr;
    a_n[j] = A[(size_t)b * HDIM + n0 + n];
    v_n[j] = v[n0 + n];
  }
#pragma unroll
  for (int f = 0; f < 4; ++f) {
#pragma unroll
    for (int r = 0; r < 4; ++r) {
      float s = 0.f;
#pragma unroll
      for (int j = 0; j < 4; ++j)
        s += v_n[j] * fast_tanh(acc[f][j][r] + a_n[j]);
      s += __shfl_xor(s, 1);
      s += __shfl_xor(s, 2);
      s += __shfl_xor(s, 4);
      s += __shfl_xor(s, 8);
      if (lr == 0) red2[wn][wm * 64 + f * 16 + lk * 4 + r] = s;
    }
  }
  __syncthreads();
  if (tid < 128)
    sp[(size_t)nblk * MTOT + m0 + tid] = red2[0][tid] + red2[1][tid];
}

// ---- softmax over s (512) per b; sums 8 partials ----
__global__ __launch_bounds__(512) void softmax8_kernel(const float* __restrict__ sp,
                                                       float* __restrict__ wts) {
  const int b = blockIdx.x, s = threadIdx.x;
  float sc = 0.f;
#pragma unroll
  for (int j = 0; j < 8; ++j) sc += sp[(size_t)j * MTOT + b * SDIM + s];
  float m = sc;
#pragma unroll
  for (int d = 1; d < 64; d <<= 1) m = fmaxf(m, __shfl_xor(m, d));
  __shared__ float redm[8], reds[8];
  if ((s & 63) == 0) redm[s >> 6] = m;
  __syncthreads();
  m = redm[0];
#pragma unroll
  for (int j = 1; j < 8; ++j) m = fmaxf(m, redm[j]);
  const float e = expf(sc - m);
  float sum = e;
#pragma unroll
  for (int d = 1; d < 64; d <<= 1) sum += __shfl_xor(sum, d);
  if ((s & 63) == 0) reds[s >> 6] = sum;
  __syncthreads();
  float tot = 0.f;
#pragma unroll
  for (int j = 0; j < 8; ++j) tot += reds[j];
  wts[(size_t)b * SDIM + s] = e / tot;
}

// ---- context[b,h] = sum_s w[b,s]*enc[b,s,h]; float2/lane ----
__global__ __launch_bounds__(256) void context_kernel(const float* __restrict__ enc,
                                                      const float* __restrict__ wts,
                                                      float* __restrict__ ctx) {
  const int hc = blockIdx.x;  // 0..1
  const int b  = blockIdx.y;  // 0..63
  const int t  = threadIdx.x;
  __shared__ float wl[SDIM];
  wl[t] = wts[(size_t)b * SDIM + t];
  wl[t + 256] = wts[(size_t)b * SDIM + 256 + t];
  __syncthreads();
  const int h = hc * 512 + t * 2;
  const float* e0 = enc + (size_t)b * SDIM * HDIM + h;
  float x0 = 0.f, y0 = 0.f, x1 = 0.f, y1 = 0.f;
  for (int s = 0; s < SDIM; s += 2) {
    const float2 v0 = *reinterpret_cast<const float2*>(e0 + (size_t)s * HDIM);
    const float2 v1 = *reinterpret_cast<const float2*>(e0 + (size_t)(s + 1) * HDIM);
    x0 += wl[s] * v0.x;     y0 += wl[s] * v0.y;
    x1 += wl[s + 1] * v1.x; y1 += wl[s + 1] * v1.y;
  }
  ctx[(size_t)b * HDIM + h]     = x0 + x1;
  ctx[(size_t)b * HDIM + h + 1] = y0 + y1;
}

extern "C" void kernel_launch(void* const* d_in, const int* in_sizes, int n_in,
                              void* d_out, int out_size, void* d_ws, size_t ws_size,
                              hipStream_t stream) {
  const float* hidden = (const float*)d_in[0];
  const float* enc    = (const float*)d_in[1];
  const float* W      = (const float*)d_in[2];
  const float* bias   = (const float*)d_in[3];
  const float* v      = (const float*)d_in[4];

  float* ctx = (float*)d_out;                // [64*1024] context
  float* wts = (float*)d_out + BDIM * HDIM;  // [64*512] attention weights

  char* ws = (char*)d_ws;
  char* w2s = ws;                                                   // 2 MB swizzled W2 tiles
  float* A  = (float*)(ws + (size_t)2 * 1024 * 1024);               // 256 KB
  float* sp = (float*)(ws + (size_t)2 * 1024 * 1024 + 256 * 1024);  // 1 MB (8 partials)

  hipLaunchKernelGGL(prep_small_kernel, dim3(768), dim3(256), 0, stream,
                     W, hidden, bias, w2s, A);
  hipLaunchKernelGGL(gemm_f32lds_kernel, dim3(2048), dim3(256), 0, stream, enc, w2s, A, v, sp);
  hipLaunchKernelGGL(softmax8_kernel, dim3(64), dim3(512), 0, stream, sp, wts);
  hipLaunchKernelGGL(context_kernel, dim3(2, 64), dim3(256), 0, stream, enc, wts, ctx);
}